// Round 9
// baseline (317.574 us; speedup 1.0000x reference)
//
#include <hip/hip_runtime.h>

#define NB 16384
#define NDOM 10
#define HIDN 512
#define STYLE 64
#define NWIN 512   // NB / 32

typedef short bf16x8 __attribute__((ext_vector_type(8)));
typedef float f32x16 __attribute__((ext_vector_type(16)));

#define MFMA __builtin_amdgcn_mfma_f32_32x32x16_bf16

// ---------------- bf16 helpers ----------------

__device__ __forceinline__ unsigned bfr_hi(float x) {
    unsigned u = __float_as_uint(x);
    return (u + 0x7fffu + ((u >> 16) & 1u)) & 0xffff0000u;  // RNE bf16 in high bits
}

__device__ __forceinline__ unsigned cvtpk(float a, float b) {
    unsigned r;
    asm("v_cvt_pk_bf16_f32 %0, %1, %2" : "=v"(r) : "v"(a), "v"(b));
    return r;   // [15:0]=bf16(a), [31:16]=bf16(b)
}

__device__ __forceinline__ void cvhalf2(const float4& x, const float4& y, uint4& h, uint4& l) {
    float xs[8] = {x.x, x.y, x.z, x.w, y.x, y.y, y.z, y.w};
    unsigned hh[8], ll[8];
#pragma unroll
    for (int i = 0; i < 8; ++i) {
        unsigned hb = bfr_hi(xs[i]);
        hh[i] = hb;
        ll[i] = bfr_hi(xs[i] - __uint_as_float(hb));
    }
    h = make_uint4((hh[0] >> 16) | (hh[1] & 0xffff0000u), (hh[2] >> 16) | (hh[3] & 0xffff0000u),
                   (hh[4] >> 16) | (hh[5] & 0xffff0000u), (hh[6] >> 16) | (hh[7] & 0xffff0000u));
    l = make_uint4((ll[0] >> 16) | (ll[1] & 0xffff0000u), (ll[2] >> 16) | (ll[3] & 0xffff0000u),
                   (ll[4] >> 16) | (ll[5] & 0xffff0000u), (ll[6] >> 16) | (ll[7] & 0xffff0000u));
}

// ---------------- weight prep + domain sort (single kernel) ----------------
// Big mats (512x512): per (mat, wq) block of 32768 shorts:
//   addr = ks*1024 + of*512 + k8*256 + c5*8 + j ; k = ks*16+k8*8+j, col = wq*64+of*32+c5
// mats: 0..2 = W1..W3 ; 3+d = Wu1[d] ; 13+d = Wu2[d] ; 23+d = Wu3[d]
// W0 (16x512): granule g: wq=g>>7, of=(g>>6)&1, k8=(g>>5)&1, c5=g&31 at W0p+g*8
// Wo (per dom 512x64): granule g: w1=g>>11, ks=(g>>6)&31, k8=(g>>5)&1, c5=g&31
// block 539: domain histogram + scan + stable scatter (rowidx, offsets)

__global__ void k_prep(const float* __restrict__ W1, const float* __restrict__ W2,
                       const float* __restrict__ W3, const float* __restrict__ Wu1,
                       const float* __restrict__ Wu2, const float* __restrict__ Wu3,
                       const float* __restrict__ W0, const float* __restrict__ Wo,
                       const int* __restrict__ y,
                       short* __restrict__ Wp, short* __restrict__ W0p,
                       short* __restrict__ WoP,
                       int* __restrict__ offsets, int* __restrict__ rowidx)
{
    const int b = blockIdx.x;
    const int t = threadIdx.x;
    if (b < 528) {
        __shared__ float Ld[64][66];
        const int mat = b >> 4, wq = (b >> 1) & 7, sh = b & 1;
        const float* src;
        if (mat < 3) src = (mat == 0 ? W1 : (mat == 1 ? W2 : W3));
        else {
            int g = (mat - 3) / 10, d = (mat - 3) % 10;
            src = (g == 0 ? Wu1 : (g == 1 ? Wu2 : Wu3)) + (size_t)d * HIDN * HIDN;
        }
        short* dst = Wp + (size_t)mat * 262144 + wq * 32768;
        for (int s = sh * 4; s < sh * 4 + 4; ++s) {
            __syncthreads();
            const int r4 = t >> 6, c = t & 63;
#pragma unroll
            for (int p = 0; p < 16; ++p) {
                int k = s * 64 + p * 4 + r4;
                Ld[p * 4 + r4][c] = src[(size_t)k * HIDN + wq * 64 + c];
            }
            __syncthreads();
#pragma unroll
            for (int i = 0; i < 2; ++i) {
                int g = i * 256 + t;
                int ksl = g >> 7, of = (g >> 6) & 1, k8 = (g >> 5) & 1, c5 = g & 31;
                int kk = ksl * 16 + k8 * 8;
                unsigned pk[4];
#pragma unroll
                for (int j2 = 0; j2 < 4; ++j2) {
                    unsigned h0 = bfr_hi(Ld[kk + 2 * j2][of * 32 + c5]);
                    unsigned h1 = bfr_hi(Ld[kk + 2 * j2 + 1][of * 32 + c5]);
                    pk[j2] = (h0 >> 16) | (h1 & 0xffff0000u);
                }
                int ksg = s * 4 + ksl;
                *(uint4*)(dst + ksg * 1024 + of * 512 + k8 * 256 + c5 * 8) =
                    make_uint4(pk[0], pk[1], pk[2], pk[3]);
            }
        }
    } else if (b == 528) {
#pragma unroll
        for (int i = 0; i < 4; ++i) {
            int g = i * 256 + t;   // 1024 granules
            int wq = g >> 7, of = (g >> 6) & 1, k8 = (g >> 5) & 1, c5 = g & 31;
            int col = wq * 64 + of * 32 + c5;
            unsigned pk[4];
#pragma unroll
            for (int j2 = 0; j2 < 4; ++j2) {
                unsigned h0 = bfr_hi(W0[(size_t)(k8 * 8 + 2 * j2) * HIDN + col]);
                unsigned h1 = bfr_hi(W0[(size_t)(k8 * 8 + 2 * j2 + 1) * HIDN + col]);
                pk[j2] = (h0 >> 16) | (h1 & 0xffff0000u);
            }
            *(uint4*)(W0p + g * 8) = make_uint4(pk[0], pk[1], pk[2], pk[3]);
        }
    } else if (b < 539) {
        const int dom = b - 529;
        const float* src = Wo + (size_t)dom * HIDN * STYLE;
        short* dst = WoP + (size_t)dom * 32768;
#pragma unroll
        for (int i = 0; i < 16; ++i) {
            int g = i * 256 + t;   // 4096 granules
            int w1 = g >> 11, ks = (g >> 6) & 31, k8 = (g >> 5) & 1, c5 = g & 31;
            int col = w1 * 32 + c5;
            int k0 = ks * 16 + k8 * 8;
            unsigned pk[4];
#pragma unroll
            for (int j2 = 0; j2 < 4; ++j2) {
                unsigned h0 = bfr_hi(src[(size_t)(k0 + 2 * j2) * STYLE + col]);
                unsigned h1 = bfr_hi(src[(size_t)(k0 + 2 * j2 + 1) * STYLE + col]);
                pk[j2] = (h0 >> 16) | (h1 & 0xffff0000u);
            }
            *(uint4*)(dst + g * 8) = make_uint4(pk[0], pk[1], pk[2], pk[3]);
        }
    } else {
        // ---- domain sort: hist + scan + stable scatter, one 256-thread block ----
        __shared__ int hist[NDOM], curx[NDOM];
        const int lane = t & 63;
        if (t < NDOM) hist[t] = 0;
        __syncthreads();
        for (int i = t; i < NB; i += 256) {
            int d = y[i];
#pragma unroll
            for (int dd = 0; dd < NDOM; ++dd) {
                unsigned long long bal = __ballot(d == dd);
                if (bal != 0ULL && d == dd && lane == __builtin_ctzll(bal))
                    atomicAdd(&hist[dd], (int)__popcll(bal));
            }
        }
        __syncthreads();
        if (t == 0) {
            int s = 0;
            for (int dd = 0; dd < NDOM; ++dd) { offsets[dd] = s; curx[dd] = s; s += hist[dd]; }
            offsets[NDOM] = s;
        }
        __syncthreads();
        for (int i = t; i < NB; i += 256) {
            int d = y[i];
#pragma unroll
            for (int dd = 0; dd < NDOM; ++dd) {
                unsigned long long bal = __ballot(d == dd);
                if (bal == 0ULL) continue;
                int leader = __builtin_ctzll(bal);
                int base = 0;
                if (d == dd && lane == leader)
                    base = atomicAdd(&curx[dd], (int)__popcll(bal));
                base = __shfl(base, leader);
                if (d == dd) {
                    int rank = (int)__popcll(bal & ((1ULL << lane) - 1ULL));
                    rowidx[base + rank] = i;
                }
            }
        }
    }
}

// ---------------- fused persistent kernel ----------------
// 512 blocks x 256 threads (4 waves), block = 32 sorted rows; 64 KB LDS ->
// TWO blocks co-resident per CU in independent barrier groups (the round-8
// structure had one 8-wave block/CU: every barrier/cold-ramp drained the CU).
// Wave w owns outcols [128w,128w+128) (of=4); rows = lane&31 (nf gone).
// h in LDS: octet o=k>>3, line = o*256 + row*8 shorts, 16B/line.
// Operand-swapped MFMA: A = weights (m=outcol), B = activations (n=batchrow).
// Weight ring depth 4 (16 b128 loads in flight); h-frags read 1 ks ahead.
// hi+lo accumulate into ONE chain (64 acc regs; issue distance 8 MFMAs).

template<bool BLO>
__device__ __forceinline__ void pass512(const short* __restrict__ sH,
                                        const short* __restrict__ sL,
                                        const short* __restrict__ pW,
                                        int w, int lane, f32x16 acc[4])
{
#pragma unroll
    for (int of = 0; of < 4; ++of)
#pragma unroll
        for (int e = 0; e < 16; ++e) acc[of][e] = 0.f;
    const int rb = (lane & 31) * 8;
    const int lh = lane >> 5;
    const short* pOf[4];
#pragma unroll
    for (int of = 0; of < 4; ++of)
        pOf[of] = pW + (2 * w + (of >> 1)) * 32768 + (of & 1) * 512 + lane * 8;
    // weight ring, depth 4 (16 dwordx4 loads in flight)
    bf16x8 wv[4][4];
#pragma unroll
    for (int d = 0; d < 4; ++d)
#pragma unroll
        for (int of = 0; of < 4; ++of)
            wv[d][of] = *(const bf16x8*)(pOf[of] + d * 1024);
    // h-frag double buffer (read 1 ks ahead)
    bf16x8 hb[2], lb[2];
    hb[0] = *(const bf16x8*)(sH + lh * 256 + rb);
    if (BLO) lb[0] = *(const bf16x8*)(sL + lh * 256 + rb);
#pragma unroll
    for (int ks = 0; ks < 32; ++ks) {
        const int pc = ks & 1, pn = pc ^ 1;
        bf16x8 wk[4];
#pragma unroll
        for (int of = 0; of < 4; ++of) wk[of] = wv[ks & 3][of];
        if (ks < 28) {
#pragma unroll
            for (int of = 0; of < 4; ++of)
                wv[ks & 3][of] = *(const bf16x8*)(pOf[of] + (ks + 4) * 1024);
        }
        if (ks < 31) {
            const int basen = (2 * (ks + 1) + lh) * 256 + rb;
            hb[pn] = *(const bf16x8*)(sH + basen);
            if (BLO) lb[pn] = *(const bf16x8*)(sL + basen);
        }
#pragma unroll
        for (int of = 0; of < 4; ++of)
            acc[of] = MFMA(wk[of], hb[pc], acc[of], 0, 0, 0);
        if (BLO) {
#pragma unroll
            for (int of = 0; of < 4; ++of)
                acc[of] = MFMA(wk[of], lb[pc], acc[of], 0, 0, 0);
        }
    }
}

// epilogue: bias (+ReLU), pack bf16 hi(/lo), shuffle-repack so each half-wave
// writes full contiguous 16B lines (conflict-free ds_write_b128).
template<bool WLO, bool RELU>
__device__ __forceinline__ void epi512(short* __restrict__ sH, short* __restrict__ sL,
                                       f32x16 acc[4],
                                       const float* __restrict__ bias,
                                       int w, int lane, int rlo, int rhi)
{
    const int lh = lane >> 5;
    const int row = lane & 31;
    const bool pred = (row >= rlo && row < rhi);
#pragma unroll
    for (int of = 0; of < 4; ++of) {
        unsigned mh[4][2], ml[4][2];
#pragma unroll
        for (int q = 0; q < 4; ++q) {
            // my 4 k-values: k = (w*4+of)*32 + q*8 + lh*4 + j
            const float4 bv = *(const float4*)&bias[(w * 4 + of) * 32 + q * 8 + lh * 4];
            float v[4];
#pragma unroll
            for (int j = 0; j < 4; ++j) {
                float x = acc[of][q * 4 + j] + (&bv.x)[j];
                if (RELU) x = fmaxf(x, 0.f);
                v[j] = x;
            }
            mh[q][0] = cvtpk(v[0], v[1]);
            mh[q][1] = cvtpk(v[2], v[3]);
            if (WLO) {
                float l0 = v[0] - __uint_as_float(mh[q][0] << 16);
                float l1 = v[1] - __uint_as_float(mh[q][0] & 0xffff0000u);
                float l2 = v[2] - __uint_as_float(mh[q][1] << 16);
                float l3 = v[3] - __uint_as_float(mh[q][1] & 0xffff0000u);
                ml[q][0] = cvtpk(l0, l1);
                ml[q][1] = cvtpk(l2, l3);
            }
        }
        // exchange with lane^32 (same row, other half of each 16B line);
        // lane writes full lines for q = 2t + lh -> contiguous per half-wave
#pragma unroll
        for (int t = 0; t < 2; ++t) {
            const int q = 2 * t + lh;
            const int qs = 2 * t + (lh ^ 1);
            unsigned r0 = (unsigned)__shfl_xor((int)mh[qs][0], 32);
            unsigned r1 = (unsigned)__shfl_xor((int)mh[qs][1], 32);
            uint4 line = lh == 0 ? make_uint4(mh[q][0], mh[q][1], r0, r1)
                                 : make_uint4(r0, r1, mh[q][0], mh[q][1]);
            const int o = (w * 4 + of) * 4 + q;
            if (pred) *(uint4*)(sH + o * 256 + row * 8) = line;
            if (WLO) {
                unsigned s0 = (unsigned)__shfl_xor((int)ml[qs][0], 32);
                unsigned s1 = (unsigned)__shfl_xor((int)ml[qs][1], 32);
                uint4 lin2 = lh == 0 ? make_uint4(ml[q][0], ml[q][1], s0, s1)
                                     : make_uint4(s0, s1, ml[q][0], ml[q][1]);
                if (pred) *(uint4*)(sL + o * 256 + row * 8) = lin2;
            }
        }
    }
}

__global__ __launch_bounds__(256, 2)
void k_fused(const float* __restrict__ z, const int* __restrict__ rowidx,
             const int* __restrict__ offsets,
             const short* __restrict__ Wp, const short* __restrict__ W0p,
             const short* __restrict__ WoP,
             const float* __restrict__ b0, const float* __restrict__ b1,
             const float* __restrict__ b2, const float* __restrict__ b3,
             const float* __restrict__ bu1, const float* __restrict__ bu2,
             const float* __restrict__ bu3, const float* __restrict__ bo,
             float* __restrict__ out)
{
    __shared__ short sH[16384];   // 32 KiB  (h hi)
    __shared__ short sL[16384];   // 32 KiB  (h lo; valid from layer-3 output on)
    __shared__ int soff[NDOM + 1];

    // XCD-chunked bijective swizzle: neighbors share a domain -> L2 reuse
    const int win = (blockIdx.x & 7) * 64 + (blockIdx.x >> 3);
    const int row0 = win * 32;
    const int tid = threadIdx.x;
    const int lane = tid & 63;
    const int w = tid >> 6;      // 0..3
    const int lh = lane >> 5;

    if (tid < NDOM + 1) soff[tid] = offsets[tid];

    f32x16 acc[4];

    // ---- layer 0: z (K=16) -> h (hi-only out; z itself split hi/lo) ----
    {
#pragma unroll
        for (int of = 0; of < 4; ++of)
#pragma unroll
            for (int e = 0; e < 16; ++e) acc[of][e] = 0.f;
        bf16x8 w0v[4];
#pragma unroll
        for (int of = 0; of < 4; ++of)
            w0v[of] = *(const bf16x8*)(W0p + (2 * w + (of >> 1)) * 1024 + (of & 1) * 512 + lane * 8);
        const int r = lane & 31;
        const int src = rowidx[row0 + r];
        const float* zp = z + (size_t)src * 16 + lh * 8;
        float4 f0 = *(const float4*)zp;
        float4 f1 = *(const float4*)(zp + 4);
        uint4 h, l;
        cvhalf2(f0, f1, h, l);
        bf16x8 zh = *(bf16x8*)&h;
        bf16x8 zl = *(bf16x8*)&l;
#pragma unroll
        for (int of = 0; of < 4; ++of) acc[of] = MFMA(w0v[of], zh, acc[of], 0, 0, 0);
#pragma unroll
        for (int of = 0; of < 4; ++of) acc[of] = MFMA(w0v[of], zl, acc[of], 0, 0, 0);
        epi512<false, true>(sH, sL, acc, b0, w, lane, 0, 32);
        __syncthreads();
    }

    // ---- trunk layers 1-3 (h hi-only inputs; layer 3 writes hi+lo) ----
#pragma unroll 1
    for (int m = 0; m < 3; ++m) {
        const float* bp = (m == 0) ? b1 : (m == 1) ? b2 : b3;
        pass512<false>(sH, sL, Wp + (size_t)m * 262144, w, lane, acc);
        __syncthreads();
        if (m < 2) epi512<false, true>(sH, sL, acc, bp, w, lane, 0, 32);
        else       epi512<true,  true>(sH, sL, acc, bp, w, lane, 0, 32);
        __syncthreads();
    }

    // ---- head layers: per-domain segments (predicated epilogue rows) ----
#pragma unroll 1
    for (int L = 0; L < 3; ++L) {
        const short* WL_ = Wp + (size_t)(3 + L * 10) * 262144;
        const float* bL = (L == 0) ? bu1 : (L == 1) ? bu2 : bu3;
#pragma unroll 1
        for (int d = 0; d < NDOM; ++d) {
            int rlo = soff[d] - row0, rhi = soff[d + 1] - row0;
            rlo = rlo < 0 ? 0 : rlo;
            rhi = rhi > 32 ? 32 : rhi;
            if (rhi <= rlo) continue;
            pass512<true>(sH, sL, WL_ + (size_t)d * 262144, w, lane, acc);
            __syncthreads();
            epi512<true, true>(sH, sL, acc, bL + d * HIDN, w, lane, rlo, rhi);
            __syncthreads();
        }
    }

    // ---- final 512->64: waves 0-1, wave = 32 outcols; coalesced float4 out ----
    if (w < 2) {
        const int r = lane & 31;
#pragma unroll 1
        for (int d = 0; d < NDOM; ++d) {
            int rlo = soff[d] - row0, rhi = soff[d + 1] - row0;
            rlo = rlo < 0 ? 0 : rlo;
            rhi = rhi > 32 ? 32 : rhi;
            if (rhi <= rlo) continue;
            f32x16 fh, fl;   // split chains here (single chain/wave otherwise)
#pragma unroll
            for (int e = 0; e < 16; ++e) { fh[e] = 0.f; fl[e] = 0.f; }
            const short* pw = WoP + (size_t)d * 32768 + w * 16384 + lane * 8;
            bf16x8 wb[4];
#pragma unroll
            for (int dd = 0; dd < 4; ++dd) wb[dd] = *(const bf16x8*)(pw + dd * 512);
#pragma unroll
            for (int ks = 0; ks < 32; ++ks) {
                bf16x8 wk = wb[ks & 3];
                if (ks < 28) wb[ks & 3] = *(const bf16x8*)(pw + (ks + 4) * 512);
                const int base = (2 * ks + lh) * 256 + (lane & 31) * 8;
                bf16x8 bhv = *(const bf16x8*)(sH + base);
                bf16x8 blv = *(const bf16x8*)(sL + base);
                fh = MFMA(wk, bhv, fh, 0, 0, 0);
                fl = MFMA(wk, blv, fl, 0, 0, 0);
            }
            if (r >= rlo && r < rhi) {
                const int orow = rowidx[row0 + r];
                float* op = out + (size_t)orow * STYLE + w * 32 + lh * 4;
                const float* bop = bo + d * STYLE + w * 32 + lh * 4;
#pragma unroll
                for (int q = 0; q < 4; ++q) {
                    float4 v;
                    v.x = fh[q * 4 + 0] + fl[q * 4 + 0] + bop[q * 8 + 0];
                    v.y = fh[q * 4 + 1] + fl[q * 4 + 1] + bop[q * 8 + 1];
                    v.z = fh[q * 4 + 2] + fl[q * 4 + 2] + bop[q * 8 + 2];
                    v.w = fh[q * 4 + 3] + fl[q * 4 + 3] + bop[q * 8 + 3];
                    *(float4*)(op + q * 8) = v;
                }
            }
        }
    }
}

// ---------------- launch ----------------

extern "C" void kernel_launch(void* const* d_in, const int* in_sizes, int n_in,
                              void* d_out, int out_size, void* d_ws, size_t ws_size,
                              hipStream_t stream) {
    const float* z   = (const float*)d_in[0];
    const int*   y   = (const int*)d_in[1];
    const float* W0  = (const float*)d_in[2];
    const float* b0  = (const float*)d_in[3];
    const float* W1  = (const float*)d_in[4];
    const float* b1  = (const float*)d_in[5];
    const float* W2  = (const float*)d_in[6];
    const float* b2  = (const float*)d_in[7];
    const float* W3  = (const float*)d_in[8];
    const float* b3  = (const float*)d_in[9];
    const float* Wu1 = (const float*)d_in[10];
    const float* bu1 = (const float*)d_in[11];
    const float* Wu2 = (const float*)d_in[12];
    const float* bu2 = (const float*)d_in[13];
    const float* Wu3 = (const float*)d_in[14];
    const float* bu3 = (const float*)d_in[15];
    const float* Wo  = (const float*)d_in[16];
    const float* bo  = (const float*)d_in[17];
    float* out = (float*)d_out;

    short* Wp   = (short*)d_ws;                      // 33 * 262144 shorts (16.5 MB)
    short* W0p  = Wp + (size_t)33 * 262144;          // 8192 shorts
    short* WoP  = W0p + 8192;                        // 10 * 32768 shorts
    int* rowidx  = (int*)(WoP + (size_t)10 * 32768); // NB ints
    int* offsets = rowidx + NB;                      // NDOM+1 ints

    k_prep<<<540, 256, 0, stream>>>(W1, W2, W3, Wu1, Wu2, Wu3, W0, Wo, y,
                                    Wp, W0p, WoP, offsets, rowidx);
    k_fused<<<NWIN, 256, 0, stream>>>(z, rowidx, offsets, Wp, W0p, WoP,
                                      b0, b1, b2, b3, bu1, bu2, bu3, bo, out);
}

// Round 10
// 227.391 us; speedup vs baseline: 1.3966x; 1.3966x over previous
//
#include <hip/hip_runtime.h>

#define NB 16384
#define NDOM 10
#define HIDN 512
#define STYLE 64
#define NWIN 512   // NB / 32

typedef short bf16x8 __attribute__((ext_vector_type(8)));
typedef float f32x16 __attribute__((ext_vector_type(16)));

#define MFMA __builtin_amdgcn_mfma_f32_32x32x16_bf16

// ---------------- bf16 helpers ----------------

__device__ __forceinline__ unsigned bfr_hi(float x) {
    unsigned u = __float_as_uint(x);
    return (u + 0x7fffu + ((u >> 16) & 1u)) & 0xffff0000u;  // RNE bf16 in high bits
}

__device__ __forceinline__ unsigned cvtpk(float a, float b) {
    unsigned r;
    asm("v_cvt_pk_bf16_f32 %0, %1, %2" : "=v"(r) : "v"(a), "v"(b));
    return r;   // [15:0]=bf16(a), [31:16]=bf16(b)
}

__device__ __forceinline__ void cvhalf2(const float4& x, const float4& y, uint4& h, uint4& l) {
    float xs[8] = {x.x, x.y, x.z, x.w, y.x, y.y, y.z, y.w};
    unsigned hh[8], ll[8];
#pragma unroll
    for (int i = 0; i < 8; ++i) {
        unsigned hb = bfr_hi(xs[i]);
        hh[i] = hb;
        ll[i] = bfr_hi(xs[i] - __uint_as_float(hb));
    }
    h = make_uint4((hh[0] >> 16) | (hh[1] & 0xffff0000u), (hh[2] >> 16) | (hh[3] & 0xffff0000u),
                   (hh[4] >> 16) | (hh[5] & 0xffff0000u), (hh[6] >> 16) | (hh[7] & 0xffff0000u));
    l = make_uint4((ll[0] >> 16) | (ll[1] & 0xffff0000u), (ll[2] >> 16) | (ll[3] & 0xffff0000u),
                   (ll[4] >> 16) | (ll[5] & 0xffff0000u), (ll[6] >> 16) | (ll[7] & 0xffff0000u));
}

// ---------------- bucketing: parallel hist + scatter (64 blocks each) ------
// Placement within a domain is atomic-order dependent, but every row's output
// value is position-independent -> d_out deterministic.

__global__ void k_hist(const int* __restrict__ y, int* __restrict__ counts) {
    int b = blockIdx.x * 256 + threadIdx.x;   // grid 64
    int d = y[b];
    int lane = threadIdx.x & 63;
#pragma unroll
    for (int dd = 0; dd < NDOM; ++dd) {
        unsigned long long bal = __ballot(d == dd);
        if (bal != 0ULL && d == dd && lane == __builtin_ctzll(bal))
            atomicAdd(&counts[dd], (int)__popcll(bal));
    }
}

__global__ void k_scatter(const int* __restrict__ y, const int* __restrict__ counts,
                          int* __restrict__ cursors, int* __restrict__ rowidx) {
    __shared__ int soff[NDOM];
    if (threadIdx.x == 0) {
        int s = 0;
        for (int dd = 0; dd < NDOM; ++dd) { soff[dd] = s; s += counts[dd]; }
    }
    __syncthreads();
    int b = blockIdx.x * 256 + threadIdx.x;   // grid 64
    int d = y[b];
    int lane = threadIdx.x & 63;
#pragma unroll
    for (int dd = 0; dd < NDOM; ++dd) {
        unsigned long long bal = __ballot(d == dd);
        if (bal == 0ULL) continue;
        int leader = __builtin_ctzll(bal);
        int base = 0;
        if (d == dd && lane == leader)
            base = atomicAdd(&cursors[dd], (int)__popcll(bal));
        base = __shfl(base, leader);
        if (d == dd) {
            int rank = (int)__popcll(bal & ((1ULL << lane) - 1ULL));
            rowidx[soff[dd] + base + rank] = b;
        }
    }
}

// ---------------- weight prep (single bf16, frag-linear) -------------------
// Big mats (512x512): per (mat, wq) block of 32768 shorts:
//   addr = ks*1024 + of*512 + k8*256 + c5*8 + j ; k = ks*16+k8*8+j, col = wq*64+of*32+c5
// mats: 0..2 = W1..W3 ; 3+d = Wu1[d] ; 13+d = Wu2[d] ; 23+d = Wu3[d]
// W0 (16x512): granule g: wq=g>>7, of=(g>>6)&1, k8=(g>>5)&1, c5=g&31 at W0p+g*8
// Wo (per dom 512x64): granule g: w1=g>>11, ks=(g>>6)&31, k8=(g>>5)&1, c5=g&31

__global__ void k_prep(const float* __restrict__ W1, const float* __restrict__ W2,
                       const float* __restrict__ W3, const float* __restrict__ Wu1,
                       const float* __restrict__ Wu2, const float* __restrict__ Wu3,
                       const float* __restrict__ W0, const float* __restrict__ Wo,
                       short* __restrict__ Wp, short* __restrict__ W0p,
                       short* __restrict__ WoP)
{
    const int b = blockIdx.x;
    const int t = threadIdx.x;
    if (b < 528) {
        __shared__ float Ld[64][66];
        const int mat = b >> 4, wq = (b >> 1) & 7, sh = b & 1;
        const float* src;
        if (mat < 3) src = (mat == 0 ? W1 : (mat == 1 ? W2 : W3));
        else {
            int g = (mat - 3) / 10, d = (mat - 3) % 10;
            src = (g == 0 ? Wu1 : (g == 1 ? Wu2 : Wu3)) + (size_t)d * HIDN * HIDN;
        }
        short* dst = Wp + (size_t)mat * 262144 + wq * 32768;
        for (int s = sh * 4; s < sh * 4 + 4; ++s) {
            __syncthreads();
            const int r4 = t >> 6, c = t & 63;
#pragma unroll
            for (int p = 0; p < 16; ++p) {
                int k = s * 64 + p * 4 + r4;
                Ld[p * 4 + r4][c] = src[(size_t)k * HIDN + wq * 64 + c];
            }
            __syncthreads();
#pragma unroll
            for (int i = 0; i < 2; ++i) {
                int g = i * 256 + t;
                int ksl = g >> 7, of = (g >> 6) & 1, k8 = (g >> 5) & 1, c5 = g & 31;
                int kk = ksl * 16 + k8 * 8;
                unsigned pk[4];
#pragma unroll
                for (int j2 = 0; j2 < 4; ++j2) {
                    unsigned h0 = bfr_hi(Ld[kk + 2 * j2][of * 32 + c5]);
                    unsigned h1 = bfr_hi(Ld[kk + 2 * j2 + 1][of * 32 + c5]);
                    pk[j2] = (h0 >> 16) | (h1 & 0xffff0000u);
                }
                int ksg = s * 4 + ksl;
                *(uint4*)(dst + ksg * 1024 + of * 512 + k8 * 256 + c5 * 8) =
                    make_uint4(pk[0], pk[1], pk[2], pk[3]);
            }
        }
    } else if (b == 528) {
#pragma unroll
        for (int i = 0; i < 4; ++i) {
            int g = i * 256 + t;   // 1024 granules
            int wq = g >> 7, of = (g >> 6) & 1, k8 = (g >> 5) & 1, c5 = g & 31;
            int col = wq * 64 + of * 32 + c5;
            unsigned pk[4];
#pragma unroll
            for (int j2 = 0; j2 < 4; ++j2) {
                unsigned h0 = bfr_hi(W0[(size_t)(k8 * 8 + 2 * j2) * HIDN + col]);
                unsigned h1 = bfr_hi(W0[(size_t)(k8 * 8 + 2 * j2 + 1) * HIDN + col]);
                pk[j2] = (h0 >> 16) | (h1 & 0xffff0000u);
            }
            *(uint4*)(W0p + g * 8) = make_uint4(pk[0], pk[1], pk[2], pk[3]);
        }
    } else {
        const int dom = b - 529;
        const float* src = Wo + (size_t)dom * HIDN * STYLE;
        short* dst = WoP + (size_t)dom * 32768;
#pragma unroll
        for (int i = 0; i < 16; ++i) {
            int g = i * 256 + t;   // 4096 granules
            int w1 = g >> 11, ks = (g >> 6) & 31, k8 = (g >> 5) & 1, c5 = g & 31;
            int col = w1 * 32 + c5;
            int k0 = ks * 16 + k8 * 8;
            unsigned pk[4];
#pragma unroll
            for (int j2 = 0; j2 < 4; ++j2) {
                unsigned h0 = bfr_hi(src[(size_t)(k0 + 2 * j2) * STYLE + col]);
                unsigned h1 = bfr_hi(src[(size_t)(k0 + 2 * j2 + 1) * STYLE + col]);
                pk[j2] = (h0 >> 16) | (h1 & 0xffff0000u);
            }
            *(uint4*)(dst + g * 8) = make_uint4(pk[0], pk[1], pk[2], pk[3]);
        }
    }
}

// ---------------- fused persistent kernel ----------------
// 512 blocks x 256 threads (4 waves), block = 32 sorted rows; 64 KB LDS ->
// TWO blocks co-resident per CU in independent barrier groups.
// Wave w owns outcols [128w,128w+128) (of=4); rows = lane&31.
// h in LDS: octet o=k>>3, line = o*256 + row*8 shorts, 16B/line.
// Operand-swapped MFMA: A = weights (m=outcol), B = activations (n=batchrow).
// Weight ring depth 4 (16 b128 loads in flight); h-frags read 1 ks ahead.
// hi+lo accumulate into ONE chain (64 acc regs; issue distance 8 MFMAs).

template<bool BLO>
__device__ __forceinline__ void pass512(const short* __restrict__ sH,
                                        const short* __restrict__ sL,
                                        const short* __restrict__ pW,
                                        int w, int lane, f32x16 acc[4])
{
#pragma unroll
    for (int of = 0; of < 4; ++of)
#pragma unroll
        for (int e = 0; e < 16; ++e) acc[of][e] = 0.f;
    const int rb = (lane & 31) * 8;
    const int lh = lane >> 5;
    const short* pOf[4];
#pragma unroll
    for (int of = 0; of < 4; ++of)
        pOf[of] = pW + (2 * w + (of >> 1)) * 32768 + (of & 1) * 512 + lane * 8;
    // weight ring, depth 4 (16 dwordx4 loads in flight)
    bf16x8 wv[4][4];
#pragma unroll
    for (int d = 0; d < 4; ++d)
#pragma unroll
        for (int of = 0; of < 4; ++of)
            wv[d][of] = *(const bf16x8*)(pOf[of] + d * 1024);
    // h-frag double buffer (read 1 ks ahead)
    bf16x8 hb[2], lb[2];
    hb[0] = *(const bf16x8*)(sH + lh * 256 + rb);
    if (BLO) lb[0] = *(const bf16x8*)(sL + lh * 256 + rb);
#pragma unroll
    for (int ks = 0; ks < 32; ++ks) {
        const int pc = ks & 1, pn = pc ^ 1;
        bf16x8 wk[4];
#pragma unroll
        for (int of = 0; of < 4; ++of) wk[of] = wv[ks & 3][of];
        if (ks < 28) {
#pragma unroll
            for (int of = 0; of < 4; ++of)
                wv[ks & 3][of] = *(const bf16x8*)(pOf[of] + (ks + 4) * 1024);
        }
        if (ks < 31) {
            const int basen = (2 * (ks + 1) + lh) * 256 + rb;
            hb[pn] = *(const bf16x8*)(sH + basen);
            if (BLO) lb[pn] = *(const bf16x8*)(sL + basen);
        }
#pragma unroll
        for (int of = 0; of < 4; ++of)
            acc[of] = MFMA(wk[of], hb[pc], acc[of], 0, 0, 0);
        if (BLO) {
#pragma unroll
            for (int of = 0; of < 4; ++of)
                acc[of] = MFMA(wk[of], lb[pc], acc[of], 0, 0, 0);
        }
    }
}

// epilogue: bias (+ReLU), pack bf16 hi(/lo), shuffle-repack so each half-wave
// writes full contiguous 16B lines (conflict-free ds_write_b128).
template<bool WLO, bool RELU>
__device__ __forceinline__ void epi512(short* __restrict__ sH, short* __restrict__ sL,
                                       f32x16 acc[4],
                                       const float* __restrict__ bias,
                                       int w, int lane, int rlo, int rhi)
{
    const int lh = lane >> 5;
    const int row = lane & 31;
    const bool pred = (row >= rlo && row < rhi);
#pragma unroll
    for (int of = 0; of < 4; ++of) {
        unsigned mh[4][2], ml[4][2];
#pragma unroll
        for (int q = 0; q < 4; ++q) {
            // my 4 k-values: k = (w*4+of)*32 + q*8 + lh*4 + j
            const float4 bv = *(const float4*)&bias[(w * 4 + of) * 32 + q * 8 + lh * 4];
            float v[4];
#pragma unroll
            for (int j = 0; j < 4; ++j) {
                float x = acc[of][q * 4 + j] + (&bv.x)[j];
                if (RELU) x = fmaxf(x, 0.f);
                v[j] = x;
            }
            mh[q][0] = cvtpk(v[0], v[1]);
            mh[q][1] = cvtpk(v[2], v[3]);
            if (WLO) {
                float l0 = v[0] - __uint_as_float(mh[q][0] << 16);
                float l1 = v[1] - __uint_as_float(mh[q][0] & 0xffff0000u);
                float l2 = v[2] - __uint_as_float(mh[q][1] << 16);
                float l3 = v[3] - __uint_as_float(mh[q][1] & 0xffff0000u);
                ml[q][0] = cvtpk(l0, l1);
                ml[q][1] = cvtpk(l2, l3);
            }
        }
        // exchange with lane^32 (same row, other half of each 16B line);
        // lane writes full lines for q = 2t + lh -> contiguous per half-wave
#pragma unroll
        for (int t = 0; t < 2; ++t) {
            const int q = 2 * t + lh;
            const int qs = 2 * t + (lh ^ 1);
            unsigned r0 = (unsigned)__shfl_xor((int)mh[qs][0], 32);
            unsigned r1 = (unsigned)__shfl_xor((int)mh[qs][1], 32);
            uint4 line = lh == 0 ? make_uint4(mh[q][0], mh[q][1], r0, r1)
                                 : make_uint4(r0, r1, mh[q][0], mh[q][1]);
            const int o = (w * 4 + of) * 4 + q;
            if (pred) *(uint4*)(sH + o * 256 + row * 8) = line;
            if (WLO) {
                unsigned s0 = (unsigned)__shfl_xor((int)ml[qs][0], 32);
                unsigned s1 = (unsigned)__shfl_xor((int)ml[qs][1], 32);
                uint4 lin2 = lh == 0 ? make_uint4(ml[q][0], ml[q][1], s0, s1)
                                     : make_uint4(s0, s1, ml[q][0], ml[q][1]);
                if (pred) *(uint4*)(sL + o * 256 + row * 8) = lin2;
            }
        }
    }
}

__global__ __launch_bounds__(256, 2)
void k_fused(const float* __restrict__ z, const int* __restrict__ rowidx,
             const int* __restrict__ counts,
             const short* __restrict__ Wp, const short* __restrict__ W0p,
             const short* __restrict__ WoP,
             const float* __restrict__ b0, const float* __restrict__ b1,
             const float* __restrict__ b2, const float* __restrict__ b3,
             const float* __restrict__ bu1, const float* __restrict__ bu2,
             const float* __restrict__ bu3, const float* __restrict__ bo,
             float* __restrict__ out)
{
    __shared__ short sH[16384];   // 32 KiB  (h hi)
    __shared__ short sL[16384];   // 32 KiB  (h lo; valid from layer-3 output on)
    __shared__ int soff[NDOM + 1];

    // XCD-chunked bijective swizzle: neighbors share a domain -> L2 reuse
    const int win = (blockIdx.x & 7) * 64 + (blockIdx.x >> 3);
    const int row0 = win * 32;
    const int tid = threadIdx.x;
    const int lane = tid & 63;
    const int w = tid >> 6;      // 0..3
    const int lh = lane >> 5;

    if (tid == 0) {
        int s = 0;
#pragma unroll
        for (int dd = 0; dd < NDOM; ++dd) { soff[dd] = s; s += counts[dd]; }
        soff[NDOM] = s;
    }
    // soff first read in the head loop — multiple __syncthreads before then

    f32x16 acc[4];

    // ---- layer 0: z (K=16) -> h (hi-only out; z itself split hi/lo) ----
    {
#pragma unroll
        for (int of = 0; of < 4; ++of)
#pragma unroll
            for (int e = 0; e < 16; ++e) acc[of][e] = 0.f;
        bf16x8 w0v[4];
#pragma unroll
        for (int of = 0; of < 4; ++of)
            w0v[of] = *(const bf16x8*)(W0p + (2 * w + (of >> 1)) * 1024 + (of & 1) * 512 + lane * 8);
        const int r = lane & 31;
        const int src = rowidx[row0 + r];
        const float* zp = z + (size_t)src * 16 + lh * 8;
        float4 f0 = *(const float4*)zp;
        float4 f1 = *(const float4*)(zp + 4);
        uint4 h, l;
        cvhalf2(f0, f1, h, l);
        bf16x8 zh = *(bf16x8*)&h;
        bf16x8 zl = *(bf16x8*)&l;
#pragma unroll
        for (int of = 0; of < 4; ++of) acc[of] = MFMA(w0v[of], zh, acc[of], 0, 0, 0);
#pragma unroll
        for (int of = 0; of < 4; ++of) acc[of] = MFMA(w0v[of], zl, acc[of], 0, 0, 0);
        epi512<false, true>(sH, sL, acc, b0, w, lane, 0, 32);
        __syncthreads();
    }

    // ---- trunk layers 1-3 (h hi-only inputs; layer 3 writes hi+lo) ----
#pragma unroll 1
    for (int m = 0; m < 3; ++m) {
        const float* bp = (m == 0) ? b1 : (m == 1) ? b2 : b3;
        pass512<false>(sH, sL, Wp + (size_t)m * 262144, w, lane, acc);
        __syncthreads();
        if (m < 2) epi512<false, true>(sH, sL, acc, bp, w, lane, 0, 32);
        else       epi512<true,  true>(sH, sL, acc, bp, w, lane, 0, 32);
        __syncthreads();
    }

    // ---- head layers: per-domain segments (predicated epilogue rows) ----
#pragma unroll 1
    for (int L = 0; L < 3; ++L) {
        const short* WL_ = Wp + (size_t)(3 + L * 10) * 262144;
        const float* bL = (L == 0) ? bu1 : (L == 1) ? bu2 : bu3;
#pragma unroll 1
        for (int d = 0; d < NDOM; ++d) {
            int rlo = soff[d] - row0, rhi = soff[d + 1] - row0;
            rlo = rlo < 0 ? 0 : rlo;
            rhi = rhi > 32 ? 32 : rhi;
            if (rhi <= rlo) continue;
            pass512<true>(sH, sL, WL_ + (size_t)d * 262144, w, lane, acc);
            __syncthreads();
            epi512<true, true>(sH, sL, acc, bL + d * HIDN, w, lane, rlo, rhi);
            __syncthreads();
        }
    }

    // ---- final 512->64: waves 0-1, wave = 32 outcols; coalesced float4 out ----
    if (w < 2) {
        const int r = lane & 31;
#pragma unroll 1
        for (int d = 0; d < NDOM; ++d) {
            int rlo = soff[d] - row0, rhi = soff[d + 1] - row0;
            rlo = rlo < 0 ? 0 : rlo;
            rhi = rhi > 32 ? 32 : rhi;
            if (rhi <= rlo) continue;
            f32x16 fh, fl;   // split chains here (single chain/wave otherwise)
#pragma unroll
            for (int e = 0; e < 16; ++e) { fh[e] = 0.f; fl[e] = 0.f; }
            const short* pw = WoP + (size_t)d * 32768 + w * 16384 + lane * 8;
            bf16x8 wb[4];
#pragma unroll
            for (int dd = 0; dd < 4; ++dd) wb[dd] = *(const bf16x8*)(pw + dd * 512);
#pragma unroll
            for (int ks = 0; ks < 32; ++ks) {
                bf16x8 wk = wb[ks & 3];
                if (ks < 28) wb[ks & 3] = *(const bf16x8*)(pw + (ks + 4) * 512);
                const int base = (2 * ks + lh) * 256 + (lane & 31) * 8;
                bf16x8 bhv = *(const bf16x8*)(sH + base);
                bf16x8 blv = *(const bf16x8*)(sL + base);
                fh = MFMA(wk, bhv, fh, 0, 0, 0);
                fl = MFMA(wk, blv, fl, 0, 0, 0);
            }
            if (r >= rlo && r < rhi) {
                const int orow = rowidx[row0 + r];
                float* op = out + (size_t)orow * STYLE + w * 32 + lh * 4;
                const float* bop = bo + d * STYLE + w * 32 + lh * 4;
#pragma unroll
                for (int q = 0; q < 4; ++q) {
                    float4 v;
                    v.x = fh[q * 4 + 0] + fl[q * 4 + 0] + bop[q * 8 + 0];
                    v.y = fh[q * 4 + 1] + fl[q * 4 + 1] + bop[q * 8 + 1];
                    v.z = fh[q * 4 + 2] + fl[q * 4 + 2] + bop[q * 8 + 2];
                    v.w = fh[q * 4 + 3] + fl[q * 4 + 3] + bop[q * 8 + 3];
                    *(float4*)(op + q * 8) = v;
                }
            }
        }
    }
}

// ---------------- launch ----------------

extern "C" void kernel_launch(void* const* d_in, const int* in_sizes, int n_in,
                              void* d_out, int out_size, void* d_ws, size_t ws_size,
                              hipStream_t stream) {
    const float* z   = (const float*)d_in[0];
    const int*   y   = (const int*)d_in[1];
    const float* W0  = (const float*)d_in[2];
    const float* b0  = (const float*)d_in[3];
    const float* W1  = (const float*)d_in[4];
    const float* b1  = (const float*)d_in[5];
    const float* W2  = (const float*)d_in[6];
    const float* b2  = (const float*)d_in[7];
    const float* W3  = (const float*)d_in[8];
    const float* b3  = (const float*)d_in[9];
    const float* Wu1 = (const float*)d_in[10];
    const float* bu1 = (const float*)d_in[11];
    const float* Wu2 = (const float*)d_in[12];
    const float* bu2 = (const float*)d_in[13];
    const float* Wu3 = (const float*)d_in[14];
    const float* bu3 = (const float*)d_in[15];
    const float* Wo  = (const float*)d_in[16];
    const float* bo  = (const float*)d_in[17];
    float* out = (float*)d_out;

    short* Wp   = (short*)d_ws;                      // 33 * 262144 shorts (16.5 MB)
    short* W0p  = Wp + (size_t)33 * 262144;          // 8192 shorts
    short* WoP  = W0p + 8192;                        // 10 * 32768 shorts
    int* rowidx  = (int*)(WoP + (size_t)10 * 32768); // NB ints
    int* counts  = rowidx + NB;                      // NDOM
    int* cursors = counts + NDOM;                    // NDOM

    hipMemsetAsync(counts, 0, sizeof(int) * 2 * NDOM, stream);
    k_hist<<<NB / 256, 256, 0, stream>>>(y, counts);
    k_scatter<<<NB / 256, 256, 0, stream>>>(y, counts, cursors, rowidx);
    k_prep<<<539, 256, 0, stream>>>(W1, W2, W3, Wu1, Wu2, Wu3, W0, Wo, Wp, W0p, WoP);
    k_fused<<<NWIN, 256, 0, stream>>>(z, rowidx, counts, Wp, W0p, WoP,
                                      b0, b1, b2, b3, bu1, bu2, bu3, bo, out);
}

// Round 11
// 195.434 us; speedup vs baseline: 1.6250x; 1.1635x over previous
//
#include <hip/hip_runtime.h>

#define NB 16384
#define NDOM 10
#define HIDN 512
#define STYLE 64
#define NWIN 512   // NB / 32

typedef short bf16x8 __attribute__((ext_vector_type(8)));
typedef float f32x16 __attribute__((ext_vector_type(16)));

#define MFMA __builtin_amdgcn_mfma_f32_32x32x16_bf16

// ---------------- bf16 helpers ----------------

__device__ __forceinline__ unsigned bfr_hi(float x) {
    unsigned u = __float_as_uint(x);
    return (u + 0x7fffu + ((u >> 16) & 1u)) & 0xffff0000u;  // RNE bf16 in high bits
}

__device__ __forceinline__ unsigned cvtpk(float a, float b) {
    unsigned r;
    asm("v_cvt_pk_bf16_f32 %0, %1, %2" : "=v"(r) : "v"(a), "v"(b));
    return r;   // [15:0]=bf16(a), [31:16]=bf16(b)
}

__device__ __forceinline__ void cvhalf2(const float4& x, const float4& y, uint4& h, uint4& l) {
    float xs[8] = {x.x, x.y, x.z, x.w, y.x, y.y, y.z, y.w};
    unsigned hh[8], ll[8];
#pragma unroll
    for (int i = 0; i < 8; ++i) {
        unsigned hb = bfr_hi(xs[i]);
        hh[i] = hb;
        ll[i] = bfr_hi(xs[i] - __uint_as_float(hb));
    }
    h = make_uint4((hh[0] >> 16) | (hh[1] & 0xffff0000u), (hh[2] >> 16) | (hh[3] & 0xffff0000u),
                   (hh[4] >> 16) | (hh[5] & 0xffff0000u), (hh[6] >> 16) | (hh[7] & 0xffff0000u));
    l = make_uint4((ll[0] >> 16) | (ll[1] & 0xffff0000u), (ll[2] >> 16) | (ll[3] & 0xffff0000u),
                   (ll[4] >> 16) | (ll[5] & 0xffff0000u), (ll[6] >> 16) | (ll[7] & 0xffff0000u));
}

// ---------------- bucketing: parallel hist + scatter (64 blocks each) ------
// Placement within a domain is atomic-order dependent, but every row's output
// value is position-independent -> d_out deterministic.

__global__ void k_hist(const int* __restrict__ y, int* __restrict__ counts) {
    int b = blockIdx.x * 256 + threadIdx.x;   // grid 64
    int d = y[b];
    int lane = threadIdx.x & 63;
#pragma unroll
    for (int dd = 0; dd < NDOM; ++dd) {
        unsigned long long bal = __ballot(d == dd);
        if (bal != 0ULL && d == dd && lane == __builtin_ctzll(bal))
            atomicAdd(&counts[dd], (int)__popcll(bal));
    }
}

__global__ void k_scatter(const int* __restrict__ y, const int* __restrict__ counts,
                          int* __restrict__ cursors, int* __restrict__ rowidx) {
    __shared__ int soff[NDOM];
    if (threadIdx.x == 0) {
        int s = 0;
        for (int dd = 0; dd < NDOM; ++dd) { soff[dd] = s; s += counts[dd]; }
    }
    __syncthreads();
    int b = blockIdx.x * 256 + threadIdx.x;   // grid 64
    int d = y[b];
    int lane = threadIdx.x & 63;
#pragma unroll
    for (int dd = 0; dd < NDOM; ++dd) {
        unsigned long long bal = __ballot(d == dd);
        if (bal == 0ULL) continue;
        int leader = __builtin_ctzll(bal);
        int base = 0;
        if (d == dd && lane == leader)
            base = atomicAdd(&cursors[dd], (int)__popcll(bal));
        base = __shfl(base, leader);
        if (d == dd) {
            int rank = (int)__popcll(bal & ((1ULL << lane) - 1ULL));
            rowidx[soff[dd] + base + rank] = b;
        }
    }
}

// ---------------- weight prep (single bf16, frag-linear) -------------------
// Big mats (512x512): per (mat, wq) block of 32768 shorts:
//   addr = ks*1024 + of*512 + k8*256 + c5*8 + j ; k = ks*16+k8*8+j, col = wq*64+of*32+c5
// mats: 0..2 = W1..W3 ; 3+d = Wu1[d] ; 13+d = Wu2[d] ; 23+d = Wu3[d]
// W0 (16x512): granule g: wq=g>>7, of=(g>>6)&1, k8=(g>>5)&1, c5=g&31 at W0p+g*8
// Wo (per dom 512x64): granule g: w1=g>>11, ks=(g>>6)&31, k8=(g>>5)&1, c5=g&31
// grid: 1056 big-mat blocks (mat, wq, sh in 0..3) + 1 W0 + 10 Wo = 1067

__global__ void k_prep(const float* __restrict__ W1, const float* __restrict__ W2,
                       const float* __restrict__ W3, const float* __restrict__ Wu1,
                       const float* __restrict__ Wu2, const float* __restrict__ Wu3,
                       const float* __restrict__ W0, const float* __restrict__ Wo,
                       short* __restrict__ Wp, short* __restrict__ W0p,
                       short* __restrict__ WoP)
{
    const int b = blockIdx.x;
    const int t = threadIdx.x;
    if (b < 1056) {
        __shared__ float Ld[64][66];
        const int mat = b >> 5, wq = (b >> 2) & 7, sh = b & 3;
        const float* src;
        if (mat < 3) src = (mat == 0 ? W1 : (mat == 1 ? W2 : W3));
        else {
            int g = (mat - 3) / 10, d = (mat - 3) % 10;
            src = (g == 0 ? Wu1 : (g == 1 ? Wu2 : Wu3)) + (size_t)d * HIDN * HIDN;
        }
        short* dst = Wp + (size_t)mat * 262144 + wq * 32768;
        for (int s = sh * 2; s < sh * 2 + 2; ++s) {
            __syncthreads();
            const int r4 = t >> 6, c = t & 63;
#pragma unroll
            for (int p = 0; p < 16; ++p) {
                int k = s * 64 + p * 4 + r4;
                Ld[p * 4 + r4][c] = src[(size_t)k * HIDN + wq * 64 + c];
            }
            __syncthreads();
#pragma unroll
            for (int i = 0; i < 2; ++i) {
                int g = i * 256 + t;
                int ksl = g >> 7, of = (g >> 6) & 1, k8 = (g >> 5) & 1, c5 = g & 31;
                int kk = ksl * 16 + k8 * 8;
                unsigned pk[4];
#pragma unroll
                for (int j2 = 0; j2 < 4; ++j2) {
                    unsigned h0 = bfr_hi(Ld[kk + 2 * j2][of * 32 + c5]);
                    unsigned h1 = bfr_hi(Ld[kk + 2 * j2 + 1][of * 32 + c5]);
                    pk[j2] = (h0 >> 16) | (h1 & 0xffff0000u);
                }
                int ksg = s * 4 + ksl;
                *(uint4*)(dst + ksg * 1024 + of * 512 + k8 * 256 + c5 * 8) =
                    make_uint4(pk[0], pk[1], pk[2], pk[3]);
            }
        }
    } else if (b == 1056) {
#pragma unroll
        for (int i = 0; i < 4; ++i) {
            int g = i * 256 + t;   // 1024 granules
            int wq = g >> 7, of = (g >> 6) & 1, k8 = (g >> 5) & 1, c5 = g & 31;
            int col = wq * 64 + of * 32 + c5;
            unsigned pk[4];
#pragma unroll
            for (int j2 = 0; j2 < 4; ++j2) {
                unsigned h0 = bfr_hi(W0[(size_t)(k8 * 8 + 2 * j2) * HIDN + col]);
                unsigned h1 = bfr_hi(W0[(size_t)(k8 * 8 + 2 * j2 + 1) * HIDN + col]);
                pk[j2] = (h0 >> 16) | (h1 & 0xffff0000u);
            }
            *(uint4*)(W0p + g * 8) = make_uint4(pk[0], pk[1], pk[2], pk[3]);
        }
    } else {
        const int dom = b - 1057;
        const float* src = Wo + (size_t)dom * HIDN * STYLE;
        short* dst = WoP + (size_t)dom * 32768;
#pragma unroll
        for (int i = 0; i < 16; ++i) {
            int g = i * 256 + t;   // 4096 granules
            int w1 = g >> 11, ks = (g >> 6) & 31, k8 = (g >> 5) & 1, c5 = g & 31;
            int col = w1 * 32 + c5;
            int k0 = ks * 16 + k8 * 8;
            unsigned pk[4];
#pragma unroll
            for (int j2 = 0; j2 < 4; ++j2) {
                unsigned h0 = bfr_hi(src[(size_t)(k0 + 2 * j2) * STYLE + col]);
                unsigned h1 = bfr_hi(src[(size_t)(k0 + 2 * j2 + 1) * STYLE + col]);
                pk[j2] = (h0 >> 16) | (h1 & 0xffff0000u);
            }
            *(uint4*)(dst + g * 8) = make_uint4(pk[0], pk[1], pk[2], pk[3]);
        }
    }
}

// ---------------- fused persistent kernel ----------------
// 512 blocks x 512 threads (8 waves), block = 32 sorted rows; 64.5 KB LDS ->
// 2 blocks/CU => 16 waves/CU = 4 waves/SIMD (2x every prior round; rounds
// 8 & 10 proved 2 waves/SIMD is latency-bound regardless of geometry).
// Wave w owns outcols [64w,64w+64) (of=2) -> ~110 regs/wave, fits the
// 128-reg budget 4 waves/SIMD requires (launch_bounds(512,4)).
// h in LDS: octet o=k>>3, line = o*256 + row*8 shorts, 16B/line.
// Operand-swapped MFMA: A = weights (m=outcol), B = activations (n=batchrow).
// Weight ring depth 4 (8 b128 loads in flight/wave, 128/CU); h-frags 1 ks ahead.
// hi+lo accumulate into ONE chain (32 acc regs).

template<bool BLO>
__device__ __forceinline__ void pass512(const short* __restrict__ sH,
                                        const short* __restrict__ sL,
                                        const short* __restrict__ pW,
                                        int w, int lane, f32x16 acc[2])
{
#pragma unroll
    for (int of = 0; of < 2; ++of)
#pragma unroll
        for (int e = 0; e < 16; ++e) acc[of][e] = 0.f;
    const int rb = (lane & 31) * 8;
    const int lh = lane >> 5;
    const short* pOf[2];
#pragma unroll
    for (int of = 0; of < 2; ++of)
        pOf[of] = pW + w * 32768 + of * 512 + lane * 8;
    // weight ring, depth 4 (8 dwordx4 loads in flight)
    bf16x8 wv[4][2];
#pragma unroll
    for (int d = 0; d < 4; ++d)
#pragma unroll
        for (int of = 0; of < 2; ++of)
            wv[d][of] = *(const bf16x8*)(pOf[of] + d * 1024);
    // h-frag double buffer (read 1 ks ahead)
    bf16x8 hb[2], lb[2];
    hb[0] = *(const bf16x8*)(sH + lh * 256 + rb);
    if (BLO) lb[0] = *(const bf16x8*)(sL + lh * 256 + rb);
#pragma unroll
    for (int ks = 0; ks < 32; ++ks) {
        const int pc = ks & 1, pn = pc ^ 1;
        bf16x8 wk[2];
        wk[0] = wv[ks & 3][0];
        wk[1] = wv[ks & 3][1];
        if (ks < 28) {
            wv[ks & 3][0] = *(const bf16x8*)(pOf[0] + (ks + 4) * 1024);
            wv[ks & 3][1] = *(const bf16x8*)(pOf[1] + (ks + 4) * 1024);
        }
        if (ks < 31) {
            const int basen = (2 * (ks + 1) + lh) * 256 + rb;
            hb[pn] = *(const bf16x8*)(sH + basen);
            if (BLO) lb[pn] = *(const bf16x8*)(sL + basen);
        }
        acc[0] = MFMA(wk[0], hb[pc], acc[0], 0, 0, 0);
        acc[1] = MFMA(wk[1], hb[pc], acc[1], 0, 0, 0);
        if (BLO) {
            acc[0] = MFMA(wk[0], lb[pc], acc[0], 0, 0, 0);
            acc[1] = MFMA(wk[1], lb[pc], acc[1], 0, 0, 0);
        }
    }
}

// epilogue: bias (+ReLU), pack bf16 hi(/lo), shuffle-repack so each half-wave
// writes full contiguous 16B lines (conflict-free ds_write_b128).
template<bool WLO, bool RELU>
__device__ __forceinline__ void epi512(short* __restrict__ sH, short* __restrict__ sL,
                                       f32x16 acc[2],
                                       const float* __restrict__ bias,
                                       int w, int lane, int rlo, int rhi)
{
    const int lh = lane >> 5;
    const int row = lane & 31;
    const bool pred = (row >= rlo && row < rhi);
#pragma unroll
    for (int of = 0; of < 2; ++of) {
        unsigned mh[4][2], ml[4][2];
#pragma unroll
        for (int q = 0; q < 4; ++q) {
            // my 4 k-values: k = (w*2+of)*32 + q*8 + lh*4 + j
            const float4 bv = *(const float4*)&bias[(w * 2 + of) * 32 + q * 8 + lh * 4];
            float v[4];
#pragma unroll
            for (int j = 0; j < 4; ++j) {
                float x = acc[of][q * 4 + j] + (&bv.x)[j];
                if (RELU) x = fmaxf(x, 0.f);
                v[j] = x;
            }
            mh[q][0] = cvtpk(v[0], v[1]);
            mh[q][1] = cvtpk(v[2], v[3]);
            if (WLO) {
                float l0 = v[0] - __uint_as_float(mh[q][0] << 16);
                float l1 = v[1] - __uint_as_float(mh[q][0] & 0xffff0000u);
                float l2 = v[2] - __uint_as_float(mh[q][1] << 16);
                float l3 = v[3] - __uint_as_float(mh[q][1] & 0xffff0000u);
                ml[q][0] = cvtpk(l0, l1);
                ml[q][1] = cvtpk(l2, l3);
            }
        }
        // exchange with lane^32 (same row, other half of each 16B line);
        // lane writes full lines for q = 2t + lh -> contiguous per half-wave
#pragma unroll
        for (int t = 0; t < 2; ++t) {
            const int q = 2 * t + lh;
            const int qs = 2 * t + (lh ^ 1);
            unsigned r0 = (unsigned)__shfl_xor((int)mh[qs][0], 32);
            unsigned r1 = (unsigned)__shfl_xor((int)mh[qs][1], 32);
            uint4 line = lh == 0 ? make_uint4(mh[q][0], mh[q][1], r0, r1)
                                 : make_uint4(r0, r1, mh[q][0], mh[q][1]);
            const int o = (w * 2 + of) * 4 + q;
            if (pred) *(uint4*)(sH + o * 256 + row * 8) = line;
            if (WLO) {
                unsigned s0 = (unsigned)__shfl_xor((int)ml[qs][0], 32);
                unsigned s1 = (unsigned)__shfl_xor((int)ml[qs][1], 32);
                uint4 lin2 = lh == 0 ? make_uint4(ml[q][0], ml[q][1], s0, s1)
                                     : make_uint4(s0, s1, ml[q][0], ml[q][1]);
                if (pred) *(uint4*)(sL + o * 256 + row * 8) = lin2;
            }
        }
    }
}

__global__ __launch_bounds__(512, 4)
void k_fused(const float* __restrict__ z, const int* __restrict__ rowidx,
             const int* __restrict__ counts,
             const short* __restrict__ Wp, const short* __restrict__ W0p,
             const short* __restrict__ WoP,
             const float* __restrict__ b0, const float* __restrict__ b1,
             const float* __restrict__ b2, const float* __restrict__ b3,
             const float* __restrict__ bu1, const float* __restrict__ bu2,
             const float* __restrict__ bu3, const float* __restrict__ bo,
             float* __restrict__ out)
{
    __shared__ short sH[16384];   // 32 KiB  (h hi)
    __shared__ short sL[16384];   // 32 KiB  (h lo; valid from layer-3 output on)
    __shared__ int soff[NDOM + 1];

    // XCD-chunked bijective swizzle: neighbors share a domain -> L2 reuse
    const int win = (blockIdx.x & 7) * 64 + (blockIdx.x >> 3);
    const int row0 = win * 32;
    const int tid = threadIdx.x;
    const int lane = tid & 63;
    const int w = tid >> 6;      // 0..7
    const int lh = lane >> 5;

    if (tid == 0) {
        int s = 0;
#pragma unroll
        for (int dd = 0; dd < NDOM; ++dd) { soff[dd] = s; s += counts[dd]; }
        soff[NDOM] = s;
    }
    // soff first read in the head loop — multiple __syncthreads before then

    f32x16 acc[2];

    // ---- layer 0: z (K=16) -> h (hi-only out; z itself split hi/lo) ----
    {
#pragma unroll
        for (int of = 0; of < 2; ++of)
#pragma unroll
            for (int e = 0; e < 16; ++e) acc[of][e] = 0.f;
        bf16x8 w0v[2];
#pragma unroll
        for (int of = 0; of < 2; ++of)
            w0v[of] = *(const bf16x8*)(W0p + w * 1024 + of * 512 + lane * 8);
        const int r = lane & 31;
        const int src = rowidx[row0 + r];
        const float* zp = z + (size_t)src * 16 + lh * 8;
        float4 f0 = *(const float4*)zp;
        float4 f1 = *(const float4*)(zp + 4);
        uint4 h, l;
        cvhalf2(f0, f1, h, l);
        bf16x8 zh = *(bf16x8*)&h;
        bf16x8 zl = *(bf16x8*)&l;
        acc[0] = MFMA(w0v[0], zh, acc[0], 0, 0, 0);
        acc[1] = MFMA(w0v[1], zh, acc[1], 0, 0, 0);
        acc[0] = MFMA(w0v[0], zl, acc[0], 0, 0, 0);
        acc[1] = MFMA(w0v[1], zl, acc[1], 0, 0, 0);
        epi512<false, true>(sH, sL, acc, b0, w, lane, 0, 32);
        __syncthreads();
    }

    // ---- trunk layers 1-3 (h hi-only inputs; layer 3 writes hi+lo) ----
#pragma unroll 1
    for (int m = 0; m < 3; ++m) {
        const float* bp = (m == 0) ? b1 : (m == 1) ? b2 : b3;
        pass512<false>(sH, sL, Wp + (size_t)m * 262144, w, lane, acc);
        __syncthreads();
        if (m < 2) epi512<false, true>(sH, sL, acc, bp, w, lane, 0, 32);
        else       epi512<true,  true>(sH, sL, acc, bp, w, lane, 0, 32);
        __syncthreads();
    }

    // ---- head layers: per-domain segments (predicated epilogue rows) ----
#pragma unroll 1
    for (int L = 0; L < 3; ++L) {
        const short* WL_ = Wp + (size_t)(3 + L * 10) * 262144;
        const float* bL = (L == 0) ? bu1 : (L == 1) ? bu2 : bu3;
#pragma unroll 1
        for (int d = 0; d < NDOM; ++d) {
            int rlo = soff[d] - row0, rhi = soff[d + 1] - row0;
            rlo = rlo < 0 ? 0 : rlo;
            rhi = rhi > 32 ? 32 : rhi;
            if (rhi <= rlo) continue;
            pass512<true>(sH, sL, WL_ + (size_t)d * 262144, w, lane, acc);
            __syncthreads();
            epi512<true, true>(sH, sL, acc, bL + d * HIDN, w, lane, rlo, rhi);
            __syncthreads();
        }
    }

    // ---- final 512->64: waves 0-1, wave = 32 outcols; coalesced float4 out ----
    if (w < 2) {
        const int r = lane & 31;
#pragma unroll 1
        for (int d = 0; d < NDOM; ++d) {
            int rlo = soff[d] - row0, rhi = soff[d + 1] - row0;
            rlo = rlo < 0 ? 0 : rlo;
            rhi = rhi > 32 ? 32 : rhi;
            if (rhi <= rlo) continue;
            f32x16 fh, fl;   // split chains here (single chain/wave otherwise)
#pragma unroll
            for (int e = 0; e < 16; ++e) { fh[e] = 0.f; fl[e] = 0.f; }
            const short* pw = WoP + (size_t)d * 32768 + w * 16384 + lane * 8;
            bf16x8 wb[4];
#pragma unroll
            for (int dd = 0; dd < 4; ++dd) wb[dd] = *(const bf16x8*)(pw + dd * 512);
#pragma unroll
            for (int ks = 0; ks < 32; ++ks) {
                bf16x8 wk = wb[ks & 3];
                if (ks < 28) wb[ks & 3] = *(const bf16x8*)(pw + (ks + 4) * 512);
                const int base = (2 * ks + lh) * 256 + (lane & 31) * 8;
                bf16x8 bhv = *(const bf16x8*)(sH + base);
                bf16x8 blv = *(const bf16x8*)(sL + base);
                fh = MFMA(wk, bhv, fh, 0, 0, 0);
                fl = MFMA(wk, blv, fl, 0, 0, 0);
            }
            if (r >= rlo && r < rhi) {
                const int orow = rowidx[row0 + r];
                float* op = out + (size_t)orow * STYLE + w * 32 + lh * 4;
                const float* bop = bo + d * STYLE + w * 32 + lh * 4;
#pragma unroll
                for (int q = 0; q < 4; ++q) {
                    float4 v;
                    v.x = fh[q * 4 + 0] + fl[q * 4 + 0] + bop[q * 8 + 0];
                    v.y = fh[q * 4 + 1] + fl[q * 4 + 1] + bop[q * 8 + 1];
                    v.z = fh[q * 4 + 2] + fl[q * 4 + 2] + bop[q * 8 + 2];
                    v.w = fh[q * 4 + 3] + fl[q * 4 + 3] + bop[q * 8 + 3];
                    *(float4*)(op + q * 8) = v;
                }
            }
        }
    }
}

// ---------------- launch ----------------

extern "C" void kernel_launch(void* const* d_in, const int* in_sizes, int n_in,
                              void* d_out, int out_size, void* d_ws, size_t ws_size,
                              hipStream_t stream) {
    const float* z   = (const float*)d_in[0];
    const int*   y   = (const int*)d_in[1];
    const float* W0  = (const float*)d_in[2];
    const float* b0  = (const float*)d_in[3];
    const float* W1  = (const float*)d_in[4];
    const float* b1  = (const float*)d_in[5];
    const float* W2  = (const float*)d_in[6];
    const float* b2  = (const float*)d_in[7];
    const float* W3  = (const float*)d_in[8];
    const float* b3  = (const float*)d_in[9];
    const float* Wu1 = (const float*)d_in[10];
    const float* bu1 = (const float*)d_in[11];
    const float* Wu2 = (const float*)d_in[12];
    const float* bu2 = (const float*)d_in[13];
    const float* Wu3 = (const float*)d_in[14];
    const float* bu3 = (const float*)d_in[15];
    const float* Wo  = (const float*)d_in[16];
    const float* bo  = (const float*)d_in[17];
    float* out = (float*)d_out;

    short* Wp   = (short*)d_ws;                      // 33 * 262144 shorts (16.5 MB)
    short* W0p  = Wp + (size_t)33 * 262144;          // 8192 shorts
    short* WoP  = W0p + 8192;                        // 10 * 32768 shorts
    int* rowidx  = (int*)(WoP + (size_t)10 * 32768); // NB ints
    int* counts  = rowidx + NB;                      // NDOM
    int* cursors = counts + NDOM;                    // NDOM

    hipMemsetAsync(counts, 0, sizeof(int) * 2 * NDOM, stream);
    k_hist<<<NB / 256, 256, 0, stream>>>(y, counts);
    k_scatter<<<NB / 256, 256, 0, stream>>>(y, counts, cursors, rowidx);
    k_prep<<<1067, 256, 0, stream>>>(W1, W2, W3, Wu1, Wu2, Wu3, W0, Wo, Wp, W0p, WoP);
    k_fused<<<NWIN, 512, 0, stream>>>(z, rowidx, counts, Wp, W0p, WoP,
                                      b0, b1, b2, b3, bu1, bu2, bu3, bo, out);
}